// Round 3
// baseline (454.126 us; speedup 1.0000x reference)
//
#include <hip/hip_runtime.h>

#define N_ROWS 65536
#define DIMS 256
#define NCLS 64

// ---- ws float-index layout (total ~16.3 MiB) ----
#define PART_SUM 0          // [256][64][256] per-block partial sums (blocks 0-127 src, 128-255 trg)
#define PART_CNT 4194304    // [256][64]
#define F_SUM_S  4210688    // [64][256]
#define F_SUM_T  4227072    // [64][256]
#define BPACK    4243456    // bf16[12][8][64][8] = 24576 floats (16B aligned)
#define ACC_OFF  4268032    // double (8B aligned)

typedef __attribute__((ext_vector_type(8))) short bf16x8;
typedef __attribute__((ext_vector_type(4))) short bf16x4;
typedef __attribute__((ext_vector_type(4))) float f32x4;

__device__ __forceinline__ short f2bf(float f) {
  unsigned u = __float_as_uint(f);
  u += 0x7fffu + ((u >> 16) & 1u);  // round-to-nearest-even
  return (short)(u >> 16);
}

__device__ __forceinline__ float wave_sum64(float v) {
#pragma unroll
  for (int m = 32; m > 0; m >>= 1) v += __shfl_xor(v, m, 64);
  return v;
}
__device__ __forceinline__ float seg_max16(float v) {
#pragma unroll
  for (int m = 8; m > 0; m >>= 1) v = fmaxf(v, __shfl_xor(v, m, 64));
  return v;
}
__device__ __forceinline__ float seg_sum16(float v) {
#pragma unroll
  for (int m = 8; m > 0; m >>= 1) v += __shfl_xor(v, m, 64);
  return v;
}

// ---------------------------------------------------------------------------
// Kernel 1: segment sums. 256 blocks (128 src, 128 trg) x 512 rows.
// One wave per row (lane = 4 dims, float4). LDS f32 atomics (ds_add_f32,
// fire-and-forget -> no RMW latency chain). Flush = plain stores to a unique
// partial slot (NO global atomics).
// ---------------------------------------------------------------------------
__global__ __launch_bounds__(256) void seg_sum_kernel(
    const float* __restrict__ src_feat, const float* __restrict__ trg_feat,
    const int* __restrict__ src_label, const int* __restrict__ trg_label,
    float* __restrict__ ws_f) {
  __shared__ float lsum[NCLS * DIMS];  // 64 KB
  __shared__ float lcnt[NCLS];
  const int tid = threadIdx.x;
  const int wave = tid >> 6;
  const int lane = tid & 63;
  const bool is_trg = blockIdx.x >= 128;
  const int blk = blockIdx.x & 127;
  const float* feat = is_trg ? trg_feat : src_feat;
  const int* label = is_trg ? trg_label : src_label;

  for (int i = tid; i < NCLS * DIMS; i += 256) lsum[i] = 0.f;
  if (tid < NCLS) lcnt[tid] = 0.f;
  __syncthreads();

  const int row0 = blk * 512 + wave * 128;
  for (int i = 0; i < 128; i += 4) {
    int lb[4];
    float4 v[4];
#pragma unroll
    for (int j = 0; j < 4; ++j) {
      const int r = row0 + i + j;
      lb[j] = label[r];
      v[j] = ((const float4*)(feat + (size_t)r * DIMS))[lane];
    }
#pragma unroll
    for (int j = 0; j < 4; ++j) {
      float* p = lsum + lb[j] * DIMS + lane * 4;
      atomicAdd(p + 0, v[j].x);
      atomicAdd(p + 1, v[j].y);
      atomicAdd(p + 2, v[j].z);
      atomicAdd(p + 3, v[j].w);
      if (lane == 0) atomicAdd(&lcnt[lb[j]], 1.f);
    }
  }
  __syncthreads();

  float4* ps = (float4*)(ws_f + PART_SUM + (size_t)blockIdx.x * 16384);
  const float4* ls = (const float4*)lsum;
#pragma unroll
  for (int j = 0; j < 16; ++j) ps[j * 256 + tid] = ls[j * 256 + tid];
  if (tid < NCLS) ws_f[PART_CNT + blockIdx.x * 64 + tid] = lcnt[tid];
}

// ---------------------------------------------------------------------------
// Kernel 2: reduce 128 partials per side -> final sums. 32 blocks x 256.
// ---------------------------------------------------------------------------
__global__ __launch_bounds__(256) void reduce_kernel(float* __restrict__ ws_f) {
  const int id = blockIdx.x * 256 + threadIdx.x;  // 0..8191 float4 outputs
  const int side = id >> 12;
  const int off4 = id & 4095;
  const float4* p =
      (const float4*)(ws_f + PART_SUM + (size_t)side * 128 * 16384) + off4;
  float4 s = make_float4(0.f, 0.f, 0.f, 0.f);
#pragma unroll 8
  for (int k = 0; k < 128; ++k) {
    const float4 v = p[(size_t)k * 4096];
    s.x += v.x; s.y += v.y; s.z += v.z; s.w += v.w;
  }
  ((float4*)(ws_f + (side ? F_SUM_T : F_SUM_S)))[off4] = s;
}

// ---------------------------------------------------------------------------
// Kernel 3: means + B-fragment pack for mfma_f32_16x16x32_bf16.
// B frag: lane l holds u[class = tile*16 + (l&15)][k = s*32 + (l>>4)*8 + j].
// 12 blocks (mat*4+tile) x 64 threads.
// ---------------------------------------------------------------------------
__global__ __launch_bounds__(64) void pack_kernel(float* __restrict__ ws_f) {
  const int bx = blockIdx.x;  // mat*4 + tile
  const int mat = bx >> 2;
  const int tile = bx & 3;
  const int lane = threadIdx.x;
  const int c = tile * 16 + (lane & 15);

  float cs = 0.f, ct = 0.f;
  for (int p = 0; p < 128; ++p) {
    cs += ws_f[PART_CNT + p * 64 + c];
    ct += ws_f[PART_CNT + (128 + p) * 64 + c];
  }

  bf16x8* out = (bf16x8*)(ws_f + BPACK);
  const float* ss_base = ws_f + F_SUM_S + c * DIMS;
  const float* st_base = ws_f + F_SUM_T + c * DIMS;

#pragma unroll
  for (int s = 0; s < 8; ++s) {
    const int k0 = s * 32 + (lane >> 4) * 8;
    bf16x8 v;
#pragma unroll
    for (int j = 0; j < 8; ++j) {
      const float ss = ss_base[k0 + j];
      const float st = st_base[k0 + j];
      float u;
      if (mat == 0) u = ss / cs;
      else if (mat == 1) u = st / ct;
      else u = (ss + st) / (cs + ct);
      v[j] = f2bf(u);
    }
    out[(bx * 8 + s) * 64 + lane] = v;
  }
}

// ---------------------------------------------------------------------------
// Kernel 4: MFMA logits + fused softmax/KL + reduce.
// 1024 blocks x 256 threads; 128 rows/block, 32 rows/wave.
// Each wave stages its 32x256 tile as bf16 into a PRIVATE 16KB LDS slice
// (XOR-swizzled 8B units: u -> u ^ (2*(r&15))), then reads A fragments with
// ds_read_b128 (conflict-free). No __syncthreads needed.
// ---------------------------------------------------------------------------
__global__ __launch_bounds__(256) void main_kernel(
    const float* __restrict__ src_feat, const float* __restrict__ trg_feat,
    const float* __restrict__ ws_f, double* __restrict__ acc_out) {
  __shared__ short tile[4 * 32 * 256];  // 64 KB
  const int tid = threadIdx.x;
  const int wave = tid >> 6;
  const int lane = tid & 63;
  const int row0 = blockIdx.x * 128 + wave * 32;
  const float* base = (row0 < N_ROWS)
                          ? src_feat + (size_t)row0 * DIMS
                          : trg_feat + (size_t)(row0 - N_ROWS) * DIMS;
  short* my = tile + wave * 8192;

  // Stage 32 rows: lane loads dims 4*lane (float4), writes bf16x4 to
  // swizzled 8B-unit (lane ^ (2*(r&15))).
#pragma unroll 8
  for (int r = 0; r < 32; ++r) {
    const float4 v = ((const float4*)(base + (size_t)r * DIMS))[lane];
    bf16x4 pk;
    pk[0] = f2bf(v.x); pk[1] = f2bf(v.y); pk[2] = f2bf(v.z); pk[3] = f2bf(v.w);
    *(bf16x4*)(my + r * 256 + ((lane ^ (2 * (r & 15))) * 4)) = pk;
  }

  const bf16x8* bp = (const bf16x8*)(ws_f + BPACK);
  f32x4 C[3][4][2];
#pragma unroll
  for (int m = 0; m < 3; ++m)
#pragma unroll
    for (int t = 0; t < 4; ++t)
#pragma unroll
      for (int g = 0; g < 2; ++g) C[m][t][g] = (f32x4){0.f, 0.f, 0.f, 0.f};

#pragma unroll
  for (int s = 0; s < 8; ++s) {
    bf16x8 a[2];
#pragma unroll
    for (int g = 0; g < 2; ++g) {
      const int rt = g * 16 + (lane & 15);
      const int c = s * 4 + (lane >> 4);  // logical 16B chunk (8 dims)
      a[g] = *(const bf16x8*)(my + rt * 256 + (c ^ (lane & 15)) * 8);
    }
#pragma unroll
    for (int mt = 0; mt < 12; ++mt) {
      const bf16x8 b = bp[(mt * 8 + s) * 64 + lane];
      C[mt >> 2][mt & 3][0] =
          __builtin_amdgcn_mfma_f32_16x16x32_bf16(a[0], b, C[mt >> 2][mt & 3][0], 0, 0, 0);
      C[mt >> 2][mt & 3][1] =
          __builtin_amdgcn_mfma_f32_16x16x32_bf16(a[1], b, C[mt >> 2][mt & 3][1], 0, 0, 0);
    }
  }

  // Epilogue: D mapping: row = g*16 + (lane>>4)*4 + r, class = t*16 + (lane&15).
  float total = 0.f;
#pragma unroll
  for (int g = 0; g < 2; ++g) {
#pragma unroll
    for (int r = 0; r < 4; ++r) {
      float va[4], vb[4], vc[4];
#pragma unroll
      for (int t = 0; t < 4; ++t) {
        va[t] = C[0][t][g][r];
        vb[t] = C[1][t][g][r];
        vc[t] = C[2][t][g][r];
      }
      float ma = fmaxf(fmaxf(va[0], va[1]), fmaxf(va[2], va[3]));
      float mb = fmaxf(fmaxf(vb[0], vb[1]), fmaxf(vb[2], vb[3]));
      float mc = fmaxf(fmaxf(vc[0], vc[1]), fmaxf(vc[2], vc[3]));
      ma = seg_max16(ma); mb = seg_max16(mb); mc = seg_max16(mc);
      float ea[4], eb[4], ec[4];
      float sa = 0.f, sb = 0.f, sc = 0.f;
#pragma unroll
      for (int t = 0; t < 4; ++t) {
        ea[t] = __expf(va[t] - ma); sa += ea[t];
        eb[t] = __expf(vb[t] - mb); sb += eb[t];
        ec[t] = __expf(vc[t] - mc); sc += ec[t];
      }
      sa = seg_sum16(sa); sb = seg_sum16(sb); sc = seg_sum16(sc);
      const float La = ma + __logf(sa);
      const float Lb = mb + __logf(sb);
      const float Lc = mc + __logf(sc);
      const float isa = 1.f / sa, isb = 1.f / sb, isc = 1.f / sc;
#pragma unroll
      for (int t = 0; t < 4; ++t) {
        const float la = va[t] - La, lb = vb[t] - Lb, lc = vc[t] - Lc;
        const float pa = ea[t] * isa, pb = eb[t] * isb, pc = ec[t] * isc;
        total += pa * ((la - lb) + (la - lc)) + pb * ((lb - la) + (lb - lc)) +
                 pc * ((lc - la) + (lc - lb));
      }
    }
  }
  total = wave_sum64(total);
  if (lane == 0) atomicAdd(acc_out, (double)total);
}

// final = sum_of_6_kl_sums / (6 * 2N * C)
__global__ void finalize_kernel(const double* __restrict__ acc,
                                float* __restrict__ out) {
  out[0] = (float)(acc[0] / 50331648.0);  // 6 * 131072 * 64
}

extern "C" void kernel_launch(void* const* d_in, const int* in_sizes, int n_in,
                              void* d_out, int out_size, void* d_ws, size_t ws_size,
                              hipStream_t stream) {
  const float* src_feat = (const float*)d_in[0];
  const float* trg_feat = (const float*)d_in[1];
  const int* src_label = (const int*)d_in[2];
  const int* trg_label = (const int*)d_in[3];
  // d_in[4] (trg_feat_un) unused by the reference loss.
  float* ws_f = (float*)d_ws;
  double* acc = (double*)(ws_f + ACC_OFF);
  float* out = (float*)d_out;

  hipMemsetAsync((void*)acc, 0, sizeof(double), stream);

  seg_sum_kernel<<<256, 256, 0, stream>>>(src_feat, trg_feat, src_label,
                                          trg_label, ws_f);
  reduce_kernel<<<32, 256, 0, stream>>>(ws_f);
  pack_kernel<<<12, 64, 0, stream>>>(ws_f);
  main_kernel<<<1024, 256, 0, stream>>>(src_feat, trg_feat, ws_f, acc);
  finalize_kernel<<<1, 1, 0, stream>>>(acc, out);
}

// Round 4
// 330.111 us; speedup vs baseline: 1.3757x; 1.3757x over previous
//
#include <hip/hip_runtime.h>
#include <hip/hip_bf16.h>

#define N_ROWS 65536
#define DIMS 256
#define NCLS 64

// ---- ws float-index layout (~16.3 MiB) ----
#define PART_SUM 0          // [256][4][64][64] per-block partial sums (0-127 src, 128-255 trg)
#define PART_CNT 4194304    // [256][64]
#define F_SUM_S  4210688    // [4][64][64]  (w, class, dim-within-w)
#define F_SUM_T  4227072    // [4][64][64]
#define F_CNT    4243456    // [2][64]
#define BPACK    4243584    // bf16[12][8][64][8] = 24576 floats (16B aligned)
#define ACC_OFF  4268160    // 64 doubles (8B aligned)

typedef __attribute__((ext_vector_type(8))) short bf16x8;
typedef __attribute__((ext_vector_type(4))) float f32x4;

__device__ __forceinline__ short f2bf(float f) {
  unsigned u = __float_as_uint(f);
  u += 0x7fffu + ((u >> 16) & 1u);  // RNE
  return (short)(u >> 16);
}
__device__ __forceinline__ unsigned pk2(float x, float y) {
  union { __hip_bfloat162 h; unsigned u; } cv;
  cv.h = __float22bfloat162_rn(make_float2(x, y));  // v_cvt_pk_bf16_f32
  return cv.u;
}
__device__ __forceinline__ bf16x8 pack8(float4 lo, float4 hi) {
  union { unsigned u[4]; bf16x8 v; } cv;
  cv.u[0] = pk2(lo.x, lo.y);
  cv.u[1] = pk2(lo.z, lo.w);
  cv.u[2] = pk2(hi.x, hi.y);
  cv.u[3] = pk2(hi.z, hi.w);
  return cv.v;
}

__device__ __forceinline__ float wave_sum64(float v) {
#pragma unroll
  for (int m = 32; m > 0; m >>= 1) v += __shfl_xor(v, m, 64);
  return v;
}
__device__ __forceinline__ float seg_max16(float v) {
#pragma unroll
  for (int m = 8; m > 0; m >>= 1) v = fmaxf(v, __shfl_xor(v, m, 64));
  return v;
}
__device__ __forceinline__ float seg_sum16(float v) {
#pragma unroll
  for (int m = 8; m > 0; m >>= 1) v += __shfl_xor(v, m, 64);
  return v;
}

// ---------------------------------------------------------------------------
// Kernel 1: segment sums, NO atomics. 256 blocks (128 src, 128 trg) x 512 rows.
// Wave w owns dims [64w,64w+64), private LDS slab (bank-conflict-free 2-way).
// 8-row batches: coalesced loads, in-register duplicate-label merge, then
// 8 pipelined ds_read + 8 ds_write (reads all precede writes -> pipelined).
// ---------------------------------------------------------------------------
__global__ __launch_bounds__(256) void seg_sum_kernel(
    const float* __restrict__ src_feat, const float* __restrict__ trg_feat,
    const int* __restrict__ src_label, const int* __restrict__ trg_label,
    float* __restrict__ ws_f) {
  __shared__ float lsum[4 * NCLS * 64];  // 64 KB, wave-private slabs
  const int tid = threadIdx.x;
  const int wave = tid >> 6;
  const int lane = tid & 63;
  const bool is_trg = blockIdx.x >= 128;
  const int blk = blockIdx.x & 127;
  const float* feat = is_trg ? trg_feat : src_feat;
  const int* label = is_trg ? trg_label : src_label;

  float* my = lsum + wave * 4096;
  float4* my4 = (float4*)my;
#pragma unroll
  for (int i = 0; i < 16; ++i) my4[i * 64 + lane] = make_float4(0.f, 0.f, 0.f, 0.f);

  const int row0 = blk * 512;
  const float* fcol = feat + wave * 64 + lane;
  float cnt = 0.f;

  for (int it = 0; it < 64; ++it) {
    const int r = row0 + it * 8;
    int lb[8];
    float v[8];
#pragma unroll
    for (int j = 0; j < 8; ++j) {
      lb[j] = label[r + j];
      v[j] = fcol[(size_t)(r + j) * DIMS];
    }
    // duplicate-label merge: last duplicate ends with the full sum, earlier
    // ones zeroed; same-address stores land in program order so the last
    // (complete) write wins.
#pragma unroll
    for (int j = 1; j < 8; ++j)
#pragma unroll
      for (int i = 0; i < j; ++i) {
        const bool eq = (lb[i] == lb[j]);
        v[j] += eq ? v[i] : 0.f;
        v[i] = eq ? 0.f : v[i];
      }
    if (wave == 0) {
#pragma unroll
      for (int j = 0; j < 8; ++j) cnt += (lb[j] == lane) ? 1.f : 0.f;
    }
    float t[8];
#pragma unroll
    for (int j = 0; j < 8; ++j) t[j] = my[lb[j] * 64 + lane];
#pragma unroll
    for (int j = 0; j < 8; ++j) my[lb[j] * 64 + lane] = t[j] + v[j];
  }
  __syncthreads();

  // flush: raw contiguous copy (lane-contiguous b128: conflict-free)
  float4* ps = (float4*)(ws_f + PART_SUM + (size_t)blockIdx.x * 16384);
  const float4* l4 = (const float4*)lsum;
#pragma unroll
  for (int k = 0; k < 16; ++k) ps[k * 256 + tid] = l4[k * 256 + tid];
  if (wave == 0) ws_f[PART_CNT + blockIdx.x * 64 + lane] = cnt;
}

// ---------------------------------------------------------------------------
// Kernel 2: reduce 128 partials per side -> final sums (+ counts in block 64).
// Blocks 0..63: 128 float4 outputs each, 2 threads split the 128-partial sum.
// ---------------------------------------------------------------------------
__global__ __launch_bounds__(256) void reduce_kernel(float* __restrict__ ws_f) {
  __shared__ float4 red[256];
  const int tid = threadIdx.x;
  if (blockIdx.x == 64) {
    if (tid < 128) {
      const int side = tid >> 6, c = tid & 63;
      float s = 0.f;
      for (int p = 0; p < 128; ++p)
        s += ws_f[PART_CNT + (side * 128 + p) * 64 + c];
      ws_f[F_CNT + tid] = s;
    }
    return;
  }
  const int id = blockIdx.x * 128 + (tid & 127);  // float4 output 0..8191
  const int side = id >> 12;
  const int off4 = id & 4095;
  const int half = tid >> 7;
  const float4* p = (const float4*)(ws_f + PART_SUM) + (size_t)(side * 128) * 4096 + off4;
  float4 s = make_float4(0.f, 0.f, 0.f, 0.f);
#pragma unroll 4
  for (int k = half * 64; k < half * 64 + 64; ++k) {
    const float4 v = p[(size_t)k * 4096];
    s.x += v.x; s.y += v.y; s.z += v.z; s.w += v.w;
  }
  red[tid] = s;
  __syncthreads();
  if (tid < 128) {
    const float4 b = red[tid + 128];
    s = red[tid];
    s.x += b.x; s.y += b.y; s.z += b.z; s.w += b.w;
    ((float4*)(ws_f + (side ? F_SUM_T : F_SUM_S)))[off4] = s;
  }
}

// ---------------------------------------------------------------------------
// Kernel 3: means + B-fragment pack for mfma_f32_16x16x32_bf16.
// B frag: lane l holds u[class = tile*16 + (l&15)][k = s*32 + (l>>4)*8 + j].
// Sums are in interleaved [w][c][64] layout; k-chunks of 8 stay contiguous.
// ---------------------------------------------------------------------------
__global__ __launch_bounds__(64) void pack_kernel(float* __restrict__ ws_f) {
  const int bx = blockIdx.x;  // mat*4 + tile
  const int mat = bx >> 2;
  const int tile = bx & 3;
  const int lane = threadIdx.x;
  const int c = tile * 16 + (lane & 15);

  const float cs = ws_f[F_CNT + c];
  const float ct = ws_f[F_CNT + 64 + c];
  const float rs = 1.f / cs, rt = 1.f / ct, rst = 1.f / (cs + ct);

  bf16x8* out = (bf16x8*)(ws_f + BPACK);
#pragma unroll
  for (int s = 0; s < 8; ++s) {
    const int k0 = s * 32 + (lane >> 4) * 8;
    const int addr = (k0 >> 6) * 4096 + c * 64 + (k0 & 63);
    bf16x8 v;
#pragma unroll
    for (int j = 0; j < 8; ++j) {
      const float ss = ws_f[F_SUM_S + addr + j];
      const float st = ws_f[F_SUM_T + addr + j];
      float u;
      if (mat == 0) u = ss * rs;
      else if (mat == 1) u = st * rt;
      else u = (ss + st) * rst;
      v[j] = f2bf(u);
    }
    out[(bx * 8 + s) * 64 + lane] = v;
  }
}

// ---------------------------------------------------------------------------
// Kernel 4: MFMA logits + fused softmax/KL + reduce.
// 2048 blocks x 256 threads; 16 rows/wave. All 16 A-loads burst up-front
// (single latency exposure), packed bf16 cvt, then pure MFMA loop with
// 4-way accumulator interleave. B (96 KB) broadcast from L2.
// ---------------------------------------------------------------------------
__global__ __launch_bounds__(256) void main_kernel(
    const float* __restrict__ src_feat, const float* __restrict__ trg_feat,
    const float* __restrict__ ws_f, double* __restrict__ acc) {
  __shared__ float bsum[4];
  const int tid = threadIdx.x;
  const int wave = tid >> 6;
  const int lane = tid & 63;
  const int row0 = blockIdx.x * 64 + wave * 16;
  const float* base = (row0 < N_ROWS)
                          ? src_feat + (size_t)row0 * DIMS
                          : trg_feat + (size_t)(row0 - N_ROWS) * DIMS;
  const float* ap = base + (lane & 15) * DIMS + (lane >> 4) * 8;

  float4 lo[8], hi[8];
#pragma unroll
  for (int s = 0; s < 8; ++s) {
    lo[s] = *(const float4*)(ap + s * 32);
    hi[s] = *(const float4*)(ap + s * 32 + 4);
  }
  bf16x8 a[8];
#pragma unroll
  for (int s = 0; s < 8; ++s) a[s] = pack8(lo[s], hi[s]);

  const bf16x8* bp = (const bf16x8*)(ws_f + BPACK);
  f32x4 C[12];
#pragma unroll
  for (int m = 0; m < 12; ++m) C[m] = (f32x4){0.f, 0.f, 0.f, 0.f};

#pragma unroll
  for (int mat = 0; mat < 3; ++mat) {
#pragma unroll
    for (int s = 0; s < 8; ++s) {
#pragma unroll
      for (int t = 0; t < 4; ++t) {
        const bf16x8 b = bp[((mat * 4 + t) * 8 + s) * 64 + lane];
        C[mat * 4 + t] =
            __builtin_amdgcn_mfma_f32_16x16x32_bf16(a[s], b, C[mat * 4 + t], 0, 0, 0);
      }
    }
  }

  // D mapping: row = (lane>>4)*4 + r, class = t*16 + (lane&15).
  float total = 0.f;
#pragma unroll
  for (int r = 0; r < 4; ++r) {
    float va[4], vb[4], vc[4];
#pragma unroll
    for (int t = 0; t < 4; ++t) {
      va[t] = C[t][r];
      vb[t] = C[4 + t][r];
      vc[t] = C[8 + t][r];
    }
    float ma = fmaxf(fmaxf(va[0], va[1]), fmaxf(va[2], va[3]));
    float mb = fmaxf(fmaxf(vb[0], vb[1]), fmaxf(vb[2], vb[3]));
    float mc = fmaxf(fmaxf(vc[0], vc[1]), fmaxf(vc[2], vc[3]));
    ma = seg_max16(ma); mb = seg_max16(mb); mc = seg_max16(mc);
    float ea[4], eb[4], ec[4];
    float sa = 0.f, sb = 0.f, sc = 0.f;
#pragma unroll
    for (int t = 0; t < 4; ++t) {
      ea[t] = __expf(va[t] - ma); sa += ea[t];
      eb[t] = __expf(vb[t] - mb); sb += eb[t];
      ec[t] = __expf(vc[t] - mc); sc += ec[t];
    }
    sa = seg_sum16(sa); sb = seg_sum16(sb); sc = seg_sum16(sc);
    const float La = ma + __logf(sa);
    const float Lb = mb + __logf(sb);
    const float Lc = mc + __logf(sc);
    const float isa = 1.f / sa, isb = 1.f / sb, isc = 1.f / sc;
#pragma unroll
    for (int t = 0; t < 4; ++t) {
      const float la = va[t] - La, lb = vb[t] - Lb, lc = vc[t] - Lc;
      const float pa = ea[t] * isa, pb = eb[t] * isb, pc = ec[t] * isc;
      total += pa * ((la - lb) + (la - lc)) + pb * ((lb - la) + (lb - lc)) +
               pc * ((lc - la) + (lc - lb));
    }
  }
  total = wave_sum64(total);
  if (lane == 0) bsum[wave] = total;
  __syncthreads();
  if (tid == 0) {
    const double t = (double)bsum[0] + bsum[1] + bsum[2] + bsum[3];
    atomicAdd(&acc[blockIdx.x & 63], t);
  }
}

// final = sum_of_6_kl_sums / (6 * 2N * C)
__global__ void finalize_kernel(const double* __restrict__ acc,
                                float* __restrict__ out) {
  double s = 0.0;
#pragma unroll
  for (int i = 0; i < 64; ++i) s += acc[i];
  out[0] = (float)(s / 50331648.0);  // 6 * 131072 * 64
}

extern "C" void kernel_launch(void* const* d_in, const int* in_sizes, int n_in,
                              void* d_out, int out_size, void* d_ws, size_t ws_size,
                              hipStream_t stream) {
  const float* src_feat = (const float*)d_in[0];
  const float* trg_feat = (const float*)d_in[1];
  const int* src_label = (const int*)d_in[2];
  const int* trg_label = (const int*)d_in[3];
  // d_in[4] (trg_feat_un) unused by the reference loss.
  float* ws_f = (float*)d_ws;
  double* acc = (double*)(ws_f + ACC_OFF);
  float* out = (float*)d_out;

  hipMemsetAsync((void*)acc, 0, 64 * sizeof(double), stream);

  seg_sum_kernel<<<256, 256, 0, stream>>>(src_feat, trg_feat, src_label,
                                          trg_label, ws_f);
  reduce_kernel<<<65, 256, 0, stream>>>(ws_f);
  pack_kernel<<<12, 64, 0, stream>>>(ws_f);
  main_kernel<<<2048, 256, 0, stream>>>(src_feat, trg_feat, ws_f, acc);
  finalize_kernel<<<1, 1, 0, stream>>>(acc, out);
}